// Round 9
// baseline (2191.790 us; speedup 1.0000x reference)
//
#include <hip/hip_runtime.h>

#define S_LEN 2048
#define CDIM 64
#define DDIM 256
#define NHEAD 24

typedef _Float16 half8 __attribute__((ext_vector_type(8)));

__device__ __forceinline__ ushort f2h(float f) {
    _Float16 h = (_Float16)f;
    return __builtin_bit_cast(ushort, h);
}
__device__ __forceinline__ float h2f(ushort u) {
    return (float)__builtin_bit_cast(_Float16, u);
}

// ---- Projection: nodes -> k/q heads 0..7. grid(4,128) block 256. f32 in/out.
__global__ __launch_bounds__(256) void kq_nodes_kernel(
    const float* __restrict__ nodes, const float* __restrict__ W,
    const float* __restrict__ b, float* __restrict__ Kf, float* __restrict__ Qf)
{
    __shared__ float As[16 * 256];
    const int tid = threadIdx.x;
    const int i0 = blockIdx.y * 16;
    const int n = blockIdx.x * 256 + tid;       // 0..1023
#pragma unroll
    for (int u = 0; u < 16; u++) {
        int idx = tid + 256 * u;                // r*256 + k
        As[idx] = nodes[i0 * 256 + idx];
    }
    __syncthreads();
    float acc[16];
    float bv = b[n];
#pragma unroll
    for (int r = 0; r < 16; r++) acc[r] = bv;
    for (int k = 0; k < 256; k++) {
        float w = W[n * 256 + k];
#pragma unroll
        for (int r = 0; r < 16; r++) acc[r] += As[r * 256 + k] * w;
    }
    int h = n >> 7, cc = n & 127;
#pragma unroll
    for (int r = 0; r < 16; r++) {
        if (cc < 64) Kf[(h * S_LEN + i0 + r) * CDIM + cc] = acc[r];
        else         Qf[(h * S_LEN + i0 + r) * CDIM + cc - 64] = acc[r];
    }
}

// ---- Projection: aux -> k/q heads 8..15. grid(4,128) block 256.
__global__ __launch_bounds__(256) void kq_aux_kernel(
    const float* __restrict__ aux, const float* __restrict__ W,
    const float* __restrict__ b, float* __restrict__ Kf, float* __restrict__ Qf)
{
    __shared__ float As[16 * 64];
    const int tid = threadIdx.x;
    const int i0 = blockIdx.y * 16;
    const int n = blockIdx.x * 256 + tid;
#pragma unroll
    for (int u = 0; u < 4; u++) {
        int idx = tid + 256 * u;                // r*64 + k
        As[idx] = aux[i0 * 64 + idx];
    }
    __syncthreads();
    float acc[16];
    float bv = b[n];
#pragma unroll
    for (int r = 0; r < 16; r++) acc[r] = bv;
    for (int k = 0; k < 64; k++) {
        float w = W[n * 64 + k];
#pragma unroll
        for (int r = 0; r < 16; r++) acc[r] += As[r * 64 + k] * w;
    }
    int h = 8 + (n >> 7), cc = n & 127;
#pragma unroll
    for (int r = 0; r < 16; r++) {
        if (cc < 64) Kf[(h * S_LEN + i0 + r) * CDIM + cc] = acc[r];
        else         Qf[(h * S_LEN + i0 + r) * CDIM + cc - 64] = acc[r];
    }
}

// ---- Projection: rot -> k/q heads 16..23. grid(4,128) block 256. no bias.
__global__ __launch_bounds__(256) void kq_rot_kernel(
    const float* __restrict__ rot, const float* __restrict__ W,
    float* __restrict__ Kf, float* __restrict__ Qf)
{
    __shared__ float Rs[16 * 4];
    const int tid = threadIdx.x;
    const int i0 = blockIdx.y * 16;
    const int n = blockIdx.x * 256 + tid;
    if (tid < 64) Rs[tid] = rot[i0 * 4 + tid];  // r*4 + k
    __syncthreads();
    float acc[16];
#pragma unroll
    for (int r = 0; r < 16; r++) acc[r] = 0.f;
#pragma unroll
    for (int k = 0; k < 4; k++) {
        float w = W[n * 4 + k];
#pragma unroll
        for (int r = 0; r < 16; r++) acc[r] += Rs[r * 4 + k] * w;
    }
    int h = 16 + (n >> 7), cc = n & 127;
#pragma unroll
    for (int r = 0; r < 16; r++) {
        if (cc < 64) Kf[(h * S_LEN + i0 + r) * CDIM + cc] = acc[r];
        else         Qf[(h * S_LEN + i0 + r) * CDIM + cc - 64] = acc[r];
    }
}

// ---- Projection: nodes -> values. grid(24,128) block 256. Vf[ht][j][d] f32.
__global__ __launch_bounds__(256) void val_kernel(
    const float* __restrict__ nodes, const float* __restrict__ W,
    const float* __restrict__ b, float* __restrict__ Vf)
{
    __shared__ float As[16 * 256];
    const int tid = threadIdx.x;
    const int i0 = blockIdx.y * 16;
    const int ht = blockIdx.x;
    const int d = tid;
    const int n = ht * 256 + d;                 // 0..6143
#pragma unroll
    for (int u = 0; u < 16; u++) {
        int idx = tid + 256 * u;
        As[idx] = nodes[i0 * 256 + idx];
    }
    __syncthreads();
    float acc[16];
    float bv = b[n];
#pragma unroll
    for (int r = 0; r < 16; r++) acc[r] = bv;
    for (int k = 0; k < 256; k++) {
        float w = W[n * 256 + k];
#pragma unroll
        for (int r = 0; r < 16; r++) acc[r] += As[r * 256 + k] * w;
    }
#pragma unroll
    for (int r = 0; r < 16; r++)
        Vf[(ht * S_LEN + i0 + r) * DDIM + d] = acc[r];
}

__global__ __launch_bounds__(256) void zero_kernel(float* __restrict__ p) {
    p[blockIdx.x * 256 + threadIdx.x] = 0.f;
}

// ---- Attention, scalar anchor. grid(24, 256): head h, 8-row i-tile.
// scores/p stored f16 in LDS (10-bit mantissa, |s|<~50 safe).
__global__ __launch_bounds__(256) void attn_kernel(
    const float* __restrict__ Kf, const float* __restrict__ Qf,
    const float* __restrict__ Vf, float* __restrict__ Oacc)
{
    __shared__ float KrowT[64 * 8];     // [c][r]
    __shared__ ushort Sc[8 * 2048];     // [r][j] scores, then p weights (f16)
    __shared__ float red[256];
    __shared__ float rowmax[8], rowsum[8];

    const int tid = threadIdx.x;
    const int h = blockIdx.x;
    const int i0 = blockIdx.y * 8;
    const float INVS8 = 0.35355339f;    // 1/sqrt(8)

#pragma unroll
    for (int u = 0; u < 2; u++) {
        int idx = tid + 256 * u;        // c*8 + r
        int c = idx >> 3, r = idx & 7;
        KrowT[idx] = Kf[(h * S_LEN + i0 + r) * CDIM + c];
    }
    __syncthreads();

    // phase 1: scores Sc[r][j] = K[i0+r] . Q[j]
    float pmax[8];
#pragma unroll
    for (int r = 0; r < 8; r++) pmax[r] = -1e30f;
#pragma unroll
    for (int u = 0; u < 8; u++) {
        int j = tid * 8 + u;
        float a[8];
#pragma unroll
        for (int r = 0; r < 8; r++) a[r] = 0.f;
        const float* Qj = &Qf[(h * S_LEN + j) * CDIM];
        for (int c = 0; c < 64; c++) {
            float qc = Qj[c];
#pragma unroll
            for (int r = 0; r < 8; r++) a[r] += KrowT[c * 8 + r] * qc;
        }
#pragma unroll
        for (int r = 0; r < 8; r++) {
            Sc[r * 2048 + j] = f2h(a[r]);
            pmax[r] = fmaxf(pmax[r], a[r]);
        }
    }
    __syncthreads();

    for (int r = 0; r < 8; r++) {
        red[tid] = pmax[r];
        __syncthreads();
        for (int off = 128; off > 0; off >>= 1) {
            if (tid < off) red[tid] = fmaxf(red[tid], red[tid + off]);
            __syncthreads();
        }
        if (tid == 0) rowmax[r] = red[0];
        __syncthreads();
    }

    // phase 2: p = exp((s - max)/sqrt(8)); row sums
    float psum[8];
#pragma unroll
    for (int r = 0; r < 8; r++) psum[r] = 0.f;
#pragma unroll
    for (int u = 0; u < 8; u++) {
        int j = tid * 8 + u;
#pragma unroll
        for (int r = 0; r < 8; r++) {
            float s = h2f(Sc[r * 2048 + j]);
            float p = __expf((s - rowmax[r]) * INVS8);
            psum[r] += p;
            Sc[r * 2048 + j] = f2h(p);
        }
    }
    __syncthreads();
    for (int r = 0; r < 8; r++) {
        red[tid] = psum[r];
        __syncthreads();
        for (int off = 128; off > 0; off >>= 1) {
            if (tid < off) red[tid] += red[tid + off];
            __syncthreads();
        }
        if (tid == 0) rowsum[r] = red[0];
        __syncthreads();
    }

    // phase 3: O[i0+r][d] += sum_j p[r][j] * V[j][d]
    const int d = tid;
    float facc[8];
#pragma unroll
    for (int r = 0; r < 8; r++) facc[r] = 0.f;
    for (int jb = 0; jb < 256; jb++) {
        float vd[8];
#pragma unroll
        for (int u = 0; u < 8; u++)
            vd[u] = Vf[(h * S_LEN + jb * 8 + u) * DDIM + d];
#pragma unroll
        for (int r = 0; r < 8; r++) {
            half8 p8 = *(const half8*)&Sc[r * 2048 + jb * 8];
#pragma unroll
            for (int u = 0; u < 8; u++) facc[r] += (float)p8[u] * vd[u];
        }
    }
#pragma unroll
    for (int r = 0; r < 8; r++)
        atomicAdd(&Oacc[(i0 + r) * DDIM + d], facc[r] / rowsum[r]);
}

__global__ __launch_bounds__(256) void convert_kernel(
    const float* __restrict__ Oacc, float* __restrict__ out)
{
    int idx = blockIdx.x * 256 + threadIdx.x;
    out[idx] = Oacc[idx];
}

extern "C" void kernel_launch(void* const* d_in, const int* in_sizes, int n_in,
                              void* d_out, int out_size, void* d_ws, size_t ws_size,
                              hipStream_t stream) {
    // Inputs: f32, dict order (size-resolution kept as a safety net).
    const float *nodes = 0, *aux = 0, *rot = 0, *W_nodes = 0, *b_nodes = 0,
                *W_aux = 0, *b_aux = 0, *W_rot = 0, *W_val = 0, *b_val = 0;
    int i1024[2] = {-1, -1};
    int n1024 = 0;
    for (int i = 0; i < n_in; ++i) {
        const float* p = (const float*)d_in[i];
        switch (in_sizes[i]) {
            case 524288:  nodes   = p; break;
            case 131072:  aux     = p; break;
            case 8192:    rot     = p; break;
            case 262144:  W_nodes = p; break;
            case 65536:   W_aux   = p; break;
            case 4096:    W_rot   = p; break;
            case 1572864: W_val   = p; break;
            case 6144:    b_val   = p; break;
            case 1024:    if (n1024 < 2) i1024[n1024] = i; n1024++; break;
            default: break;
        }
    }
    if (n1024 == 2) {
        b_nodes = (const float*)d_in[i1024[0]];
        b_aux   = (const float*)d_in[i1024[1]];
    }
    if (!nodes || !aux || !rot || !W_nodes || !b_nodes || !W_aux || !b_aux ||
        !W_rot || !W_val || !b_val) {
        nodes   = (const float*)d_in[0];
        aux     = (const float*)d_in[1];
        rot     = (const float*)d_in[2];
        W_nodes = (const float*)d_in[3];
        b_nodes = (const float*)d_in[4];
        W_aux   = (const float*)d_in[5];
        b_aux   = (const float*)d_in[6];
        W_rot   = (const float*)d_in[7];
        W_val   = (const float*)d_in[8];
        b_val   = (const float*)d_in[9];
    }
    float* out = (float*)d_out;   // reference output dtype is float32

    // ws: Oacc (2MB) | Kf (12.6MB) | Qf (12.6MB) | Vf (50.3MB)  = 77.6MB
    float* Oacc = (float*)d_ws;
    float* Kf = Oacc + S_LEN * DDIM;
    float* Qf = Kf + NHEAD * S_LEN * CDIM;
    float* Vf = Qf + NHEAD * S_LEN * CDIM;

    dim3 blk(256);
    zero_kernel<<<dim3(S_LEN * DDIM / 256), blk, 0, stream>>>(Oacc);
    kq_nodes_kernel<<<dim3(4, 128), blk, 0, stream>>>(nodes, W_nodes, b_nodes, Kf, Qf);
    kq_aux_kernel<<<dim3(4, 128), blk, 0, stream>>>(aux, W_aux, b_aux, Kf, Qf);
    kq_rot_kernel<<<dim3(4, 128), blk, 0, stream>>>(rot, W_rot, Kf, Qf);
    val_kernel<<<dim3(24, 128), blk, 0, stream>>>(nodes, W_val, b_val, Vf);
    attn_kernel<<<dim3(24, 256), blk, 0, stream>>>(Kf, Qf, Vf, Oacc);
    convert_kernel<<<dim3(2048), blk, 0, stream>>>(Oacc, out);
}

// Round 10
// 445.939 us; speedup vs baseline: 4.9150x; 4.9150x over previous
//
#include <hip/hip_runtime.h>

#define S_LEN 2048
#define NHEAD 24
#define CDIM 64
#define DDIM 256

typedef _Float16 f16x8 __attribute__((ext_vector_type(8)));
typedef float f32x4 __attribute__((ext_vector_type(4)));

__device__ __forceinline__ ushort f2h(float f) {
    _Float16 h = (_Float16)f;
    return __builtin_bit_cast(ushort, h);
}

// pack 8 consecutive f32 -> 8 f16 (register ops only)
__device__ __forceinline__ int4 cvt8(const float* __restrict__ p) {
    float4 a = *(const float4*)p;
    float4 b = *(const float4*)(p + 4);
    f16x8 h;
    h[0] = (_Float16)a.x; h[1] = (_Float16)a.y;
    h[2] = (_Float16)a.z; h[3] = (_Float16)a.w;
    h[4] = (_Float16)b.x; h[5] = (_Float16)b.y;
    h[6] = (_Float16)b.z; h[7] = (_Float16)b.w;
    return __builtin_bit_cast(int4, h);
}

// C = A (MxK,f32) @ W^T (NxK,f32) + bias, MFMA f16 16x16x32, 64x64 tile, 4 waves.
// mode 0: scatter f16 into Kbuf/Qbuf ([h][i][c]); mode 1: scatter f16 into Vt ([h][d][j]).
__global__ __launch_bounds__(256) void gemm_bt_kernel(
    const float* __restrict__ A, const float* __restrict__ W,
    const float* __restrict__ bias, int M, int N, int K,
    int mode, int hbase,
    ushort* __restrict__ Kbuf, ushort* __restrict__ Qbuf, ushort* __restrict__ Vt)
{
    __shared__ ushort Asub[64 * 32];
    __shared__ ushort Wsub[64 * 32];
    const int tid = threadIdx.x;
    const int wave = tid >> 6, lane = tid & 63;
    const int g = lane >> 4, c = lane & 15;
    const int m0 = blockIdx.y * 64, n0 = blockIdx.x * 64;
    const int srow = tid >> 2;          // 0..63
    const int skk = (tid & 3) * 8;      // 0,8,16,24

    f32x4 acc[4] = {f32x4{0,0,0,0}, f32x4{0,0,0,0}, f32x4{0,0,0,0}, f32x4{0,0,0,0}};

    for (int k0 = 0; k0 < K; k0 += 32) {
        __syncthreads();
        *(int4*)&Asub[srow * 32 + skk] = cvt8(&A[(m0 + srow) * K + k0 + skk]);
        *(int4*)&Wsub[srow * 32 + skk] = cvt8(&W[(n0 + srow) * K + k0 + skk]);
        __syncthreads();
        f16x8 af = *(const f16x8*)&Asub[(wave * 16 + c) * 32 + g * 8];
#pragma unroll
        for (int t = 0; t < 4; t++) {
            f16x8 bf = *(const f16x8*)&Wsub[(t * 16 + c) * 32 + g * 8];
            acc[t] = __builtin_amdgcn_mfma_f32_16x16x32_f16(af, bf, acc[t], 0, 0, 0);
        }
    }

#pragma unroll
    for (int t = 0; t < 4; t++) {
        int n = n0 + t * 16 + c;
        float bv = bias[n];
#pragma unroll
        for (int r = 0; r < 4; r++) {
            int m = m0 + wave * 16 + g * 4 + r;
            ushort u = f2h(acc[t][r] + bv);
            if (mode == 0) {
                int h = hbase + (n >> 7);
                int cc = n & 127;
                if (cc < 64) Kbuf[(h * S_LEN + m) * CDIM + cc] = u;
                else         Qbuf[(h * S_LEN + m) * CDIM + cc - 64] = u;
            } else {
                int h = n >> 8;
                int d = n & 255;
                Vt[(h * DDIM + d) * S_LEN + m] = u;
            }
        }
    }
}

// rot projection: K=4, no bias, f32 math. n = h'*128 + cc, h = 16 + h'
__global__ __launch_bounds__(256) void rot_proj_kernel(
    const float* __restrict__ rot, const float* __restrict__ Wrot,
    ushort* __restrict__ Kbuf, ushort* __restrict__ Qbuf)
{
    int idx = blockIdx.x * 256 + threadIdx.x;   // 2048*1024
    int i = idx >> 10, n = idx & 1023;
    float4 r = *(const float4*)&rot[i * 4];
    float4 w = *(const float4*)&Wrot[n * 4];
    float v = r.x * w.x + r.y * w.y + r.z * w.z + r.w * w.w;
    int h = 16 + (n >> 7), cc = n & 127;
    ushort u = f2h(v);
    if (cc < 64) Kbuf[(h * S_LEN + i) * CDIM + cc] = u;
    else         Qbuf[(h * S_LEN + i) * CDIM + cc - 64] = u;
}

__global__ __launch_bounds__(256) void zero_kernel(float* __restrict__ p) {
    p[blockIdx.x * 256 + threadIdx.x] = 0.f;
}

// Flash attention per (head, 64-row i-tile). Block = 4 waves, wave owns 16 i-rows.
// O[i][d] = sum_j softmax_j(K[i]·Q[j]/sqrt(8)) * V[j][d]; atomicAdd into Oacc (f32).
__global__ __launch_bounds__(256) void flash_kernel(
    const ushort* __restrict__ Kbuf, const ushort* __restrict__ Qbuf,
    const ushort* __restrict__ Vt, float* __restrict__ Oacc)
{
    __shared__ ushort Qlds[64 * 64];     // [j'][c]
    __shared__ ushort Vlds[256 * 64];    // [d][j']
    __shared__ ushort Plds[4][16 * 64];  // per wave: [i'][j']

    const int tid = threadIdx.x;
    const int wave = tid >> 6, lane = tid & 63;
    const int g = lane >> 4, c = lane & 15;
    const int h = blockIdx.y;
    const int i0 = blockIdx.x * 64 + wave * 16;
    const float SC = 0.51006973f;        // log2(e)/sqrt(8)

    const ushort* Krow = &Kbuf[(h * S_LEN + i0 + c) * CDIM + g * 8];
    f16x8 ka0 = *(const f16x8*)Krow;
    f16x8 ka1 = *(const f16x8*)(Krow + 32);

    f32x4 acc[16];
#pragma unroll
    for (int t = 0; t < 16; t++) acc[t] = f32x4{0, 0, 0, 0};
    float mrow[4] = {-1e30f, -1e30f, -1e30f, -1e30f};
    float lrow[4] = {0.f, 0.f, 0.f, 0.f};

    for (int j0 = 0; j0 < S_LEN; j0 += 64) {
        __syncthreads();   // previous iter's LDS reads complete before restage
        {
            const int4* Qg = (const int4*)&Qbuf[(h * S_LEN + j0) * CDIM];
            int4* Ql = (int4*)Qlds;
            Ql[tid] = Qg[tid];
            Ql[tid + 256] = Qg[tid + 256];
            // V tile: 256 rows (d) x 64 cols (j'), 8 int4 per row, 2048 int4 total
            int4* Vl = (int4*)Vlds;
#pragma unroll
            for (int q = 0; q < 8; q++) {
                int i4 = tid + 256 * q;          // 0..2047
                int d = i4 >> 3, jq = i4 & 7;    // row, 8-ushort chunk
                Vl[i4] = *(const int4*)&Vt[(h * DDIM + d) * S_LEN + j0 + jq * 8];
            }
        }
        __syncthreads();

        // scores: S[i'][j'] for 16 rows x 64 cols, 4 j-chunks
        f32x4 Sf[4];
#pragma unroll
        for (int jc = 0; jc < 4; jc++) {
            const ushort* Qr = &Qlds[(jc * 16 + c) * 64 + g * 8];
            f16x8 qb0 = *(const f16x8*)Qr;
            f16x8 qb1 = *(const f16x8*)(Qr + 32);
            f32x4 s = {0, 0, 0, 0};
            s = __builtin_amdgcn_mfma_f32_16x16x32_f16(ka0, qb0, s, 0, 0, 0);
            s = __builtin_amdgcn_mfma_f32_16x16x32_f16(ka1, qb1, s, 0, 0, 0);
#pragma unroll
            for (int r = 0; r < 4; r++) Sf[jc][r] = s[r] * SC;   // exp2 domain
        }

        // online softmax: row stats live in lanes sharing g (16-lane groups)
        float nm[4], alpha[4], rs[4];
#pragma unroll
        for (int r = 0; r < 4; r++)
            nm[r] = fmaxf(fmaxf(Sf[0][r], Sf[1][r]), fmaxf(Sf[2][r], Sf[3][r]));
#pragma unroll
        for (int off = 1; off < 16; off <<= 1)
#pragma unroll
            for (int r = 0; r < 4; r++) nm[r] = fmaxf(nm[r], __shfl_xor(nm[r], off));
#pragma unroll
        for (int r = 0; r < 4; r++) {
            nm[r] = fmaxf(nm[r], mrow[r]);
            alpha[r] = exp2f(mrow[r] - nm[r]);
            rs[r] = 0.f;
        }
#pragma unroll
        for (int jc = 0; jc < 4; jc++)
#pragma unroll
            for (int r = 0; r < 4; r++) {
                float p = exp2f(Sf[jc][r] - nm[r]);
                rs[r] += p;
                Plds[wave][(g * 4 + r) * 64 + jc * 16 + c] = f2h(p);
            }
#pragma unroll
        for (int off = 1; off < 16; off <<= 1)
#pragma unroll
            for (int r = 0; r < 4; r++) rs[r] += __shfl_xor(rs[r], off);
#pragma unroll
        for (int r = 0; r < 4; r++) {
            lrow[r] = lrow[r] * alpha[r] + rs[r];
            mrow[r] = nm[r];
        }
#pragma unroll
        for (int t = 0; t < 16; t++)
#pragma unroll
            for (int r = 0; r < 4; r++) acc[t][r] *= alpha[r];

        __syncthreads();   // Plds visible (and keeps waves in step)

        // PV: P (16x64) @ V (64x256)
        f16x8 pa0 = *(const f16x8*)&Plds[wave][c * 64 + g * 8];
        f16x8 pa1 = *(const f16x8*)&Plds[wave][c * 64 + 32 + g * 8];
#pragma unroll
        for (int t = 0; t < 16; t++) {
            f16x8 vb0 = *(const f16x8*)&Vlds[(t * 16 + c) * 64 + g * 8];
            f16x8 vb1 = *(const f16x8*)&Vlds[(t * 16 + c) * 64 + 32 + g * 8];
            acc[t] = __builtin_amdgcn_mfma_f32_16x16x32_f16(pa0, vb0, acc[t], 0, 0, 0);
            acc[t] = __builtin_amdgcn_mfma_f32_16x16x32_f16(pa1, vb1, acc[t], 0, 0, 0);
        }
    }

    // accumulate head partial into shared f32 output (24 heads -> same address)
#pragma unroll
    for (int t = 0; t < 16; t++)
#pragma unroll
        for (int r = 0; r < 4; r++) {
            int i = i0 + g * 4 + r;
            int d = t * 16 + c;
            atomicAdd(&Oacc[i * DDIM + d], acc[t][r] / lrow[r]);
        }
}

__global__ __launch_bounds__(256) void convert_kernel(
    const float* __restrict__ Oacc, float* __restrict__ out)
{
    int idx = blockIdx.x * 256 + threadIdx.x;   // 2048*256
    out[idx] = Oacc[idx];
}

extern "C" void kernel_launch(void* const* d_in, const int* in_sizes, int n_in,
                              void* d_out, int out_size, void* d_ws, size_t ws_size,
                              hipStream_t stream) {
    // Inputs: f32, resolved by element count (safety net), dict-order fallback.
    const float *nodes = 0, *aux = 0, *rot = 0, *W_nodes = 0, *b_nodes = 0,
                *W_aux = 0, *b_aux = 0, *W_rot = 0, *W_val = 0, *b_val = 0;
    int i1024[2] = {-1, -1};
    int n1024 = 0;
    for (int i = 0; i < n_in; ++i) {
        const float* p = (const float*)d_in[i];
        switch (in_sizes[i]) {
            case 524288:  nodes   = p; break;
            case 131072:  aux     = p; break;
            case 8192:    rot     = p; break;
            case 262144:  W_nodes = p; break;
            case 65536:   W_aux   = p; break;
            case 4096:    W_rot   = p; break;
            case 1572864: W_val   = p; break;
            case 6144:    b_val   = p; break;
            case 1024:    if (n1024 < 2) i1024[n1024] = i; n1024++; break;
            default: break;
        }
    }
    if (n1024 == 2) {
        b_nodes = (const float*)d_in[i1024[0]];
        b_aux   = (const float*)d_in[i1024[1]];
    }
    if (!nodes || !aux || !rot || !W_nodes || !b_nodes || !W_aux || !b_aux ||
        !W_rot || !W_val || !b_val) {
        nodes   = (const float*)d_in[0];
        aux     = (const float*)d_in[1];
        rot     = (const float*)d_in[2];
        W_nodes = (const float*)d_in[3];
        b_nodes = (const float*)d_in[4];
        W_aux   = (const float*)d_in[5];
        b_aux   = (const float*)d_in[6];
        W_rot   = (const float*)d_in[7];
        W_val   = (const float*)d_in[8];
        b_val   = (const float*)d_in[9];
    }
    float* out = (float*)d_out;   // reference output dtype is float32

    // ws layout: Oacc f32 (2MB) | K f16 (6.29MB) | Q f16 (6.29MB) | Vt f16 (25.2MB)
    float*  Oacc = (float*)d_ws;
    ushort* Kbuf = (ushort*)(Oacc + S_LEN * DDIM);
    ushort* Qbuf = Kbuf + NHEAD * S_LEN * CDIM;
    ushort* Vt   = Qbuf + NHEAD * S_LEN * CDIM;

    dim3 blk(256);
    zero_kernel<<<dim3(S_LEN * DDIM / 256), blk, 0, stream>>>(Oacc);
    // nodes -> k/q heads 0..7:  M=2048 N=1024 K=256
    gemm_bt_kernel<<<dim3(16, 32), blk, 0, stream>>>(nodes, W_nodes, b_nodes,
        2048, 1024, 256, 0, 0, Kbuf, Qbuf, nullptr);
    // aux -> k/q heads 8..15:  M=2048 N=1024 K=64
    gemm_bt_kernel<<<dim3(16, 32), blk, 0, stream>>>(aux, W_aux, b_aux,
        2048, 1024, 64, 0, 8, Kbuf, Qbuf, nullptr);
    // rot -> k/q heads 16..23 (K=4, no bias)
    rot_proj_kernel<<<dim3(8192), blk, 0, stream>>>(rot, W_rot, Kbuf, Qbuf);
    // nodes -> values, transposed write: M=2048 N=6144 K=256
    gemm_bt_kernel<<<dim3(96, 32), blk, 0, stream>>>(nodes, W_val, b_val,
        2048, 6144, 256, 1, 0, nullptr, nullptr, Vt);
    // attention: 24 heads x 32 i-tiles, accumulate into Oacc
    flash_kernel<<<dim3(32, NHEAD), blk, 0, stream>>>(Kbuf, Qbuf, Vt, Oacc);
    // f32 copy to out
    convert_kernel<<<dim3(2048), blk, 0, stream>>>(Oacc, out);
}

// Round 11
// 395.944 us; speedup vs baseline: 5.5356x; 1.1263x over previous
//
#include <hip/hip_runtime.h>

#define S_LEN 2048
#define NHEAD 24
#define CDIM 64
#define DDIM 256

typedef _Float16 f16x8 __attribute__((ext_vector_type(8)));
typedef float f32x4 __attribute__((ext_vector_type(4)));

__device__ __forceinline__ ushort f2h(float f) {
    _Float16 h = (_Float16)f;
    return __builtin_bit_cast(ushort, h);
}

// pack 8 consecutive f32 -> 8 f16 (register ops only)
__device__ __forceinline__ int4 cvt8(const float* __restrict__ p) {
    float4 a = *(const float4*)p;
    float4 b = *(const float4*)(p + 4);
    f16x8 h;
    h[0] = (_Float16)a.x; h[1] = (_Float16)a.y;
    h[2] = (_Float16)a.z; h[3] = (_Float16)a.w;
    h[4] = (_Float16)b.x; h[5] = (_Float16)b.y;
    h[6] = (_Float16)b.z; h[7] = (_Float16)b.w;
    return __builtin_bit_cast(int4, h);
}

// C = A (MxK,f32) @ W^T (NxK,f32) + bias, MFMA f16 16x16x32, 64x64 tile, 4 waves.
// LDS rows padded 32->40 ushorts: bank = 4*((5*row + k) % 8) pattern, conflict-free.
// mode 0: scatter f16 into Kbuf/Qbuf ([h][i][c]); mode 1: scatter f16 into Vt ([h][d][j]).
__global__ __launch_bounds__(256) void gemm_bt_kernel(
    const float* __restrict__ A, const float* __restrict__ W,
    const float* __restrict__ bias, int M, int N, int K,
    int mode, int hbase,
    ushort* __restrict__ Kbuf, ushort* __restrict__ Qbuf, ushort* __restrict__ Vt)
{
    __shared__ ushort Asub[64 * 40];
    __shared__ ushort Wsub[64 * 40];
    const int tid = threadIdx.x;
    const int wave = tid >> 6, lane = tid & 63;
    const int g = lane >> 4, c = lane & 15;
    const int m0 = blockIdx.y * 64, n0 = blockIdx.x * 64;
    const int srow = tid >> 2;          // 0..63
    const int skk = (tid & 3) * 8;      // 0,8,16,24

    f32x4 acc[4] = {f32x4{0,0,0,0}, f32x4{0,0,0,0}, f32x4{0,0,0,0}, f32x4{0,0,0,0}};

    for (int k0 = 0; k0 < K; k0 += 32) {
        __syncthreads();
        *(int4*)&Asub[srow * 40 + skk] = cvt8(&A[(m0 + srow) * K + k0 + skk]);
        *(int4*)&Wsub[srow * 40 + skk] = cvt8(&W[(n0 + srow) * K + k0 + skk]);
        __syncthreads();
        f16x8 af = *(const f16x8*)&Asub[(wave * 16 + c) * 40 + g * 8];
#pragma unroll
        for (int t = 0; t < 4; t++) {
            f16x8 bf = *(const f16x8*)&Wsub[(t * 16 + c) * 40 + g * 8];
            acc[t] = __builtin_amdgcn_mfma_f32_16x16x32_f16(af, bf, acc[t], 0, 0, 0);
        }
    }

#pragma unroll
    for (int t = 0; t < 4; t++) {
        int n = n0 + t * 16 + c;
        float bv = bias[n];
#pragma unroll
        for (int r = 0; r < 4; r++) {
            int m = m0 + wave * 16 + g * 4 + r;
            ushort u = f2h(acc[t][r] + bv);
            if (mode == 0) {
                int h = hbase + (n >> 7);
                int cc = n & 127;
                if (cc < 64) Kbuf[(h * S_LEN + m) * CDIM + cc] = u;
                else         Qbuf[(h * S_LEN + m) * CDIM + cc - 64] = u;
            } else {
                int h = n >> 8;
                int d = n & 255;
                Vt[(h * DDIM + d) * S_LEN + m] = u;
            }
        }
    }
}

// rot projection: K=4, no bias, f32 math. n = h'*128 + cc, h = 16 + h'
__global__ __launch_bounds__(256) void rot_proj_kernel(
    const float* __restrict__ rot, const float* __restrict__ Wrot,
    ushort* __restrict__ Kbuf, ushort* __restrict__ Qbuf)
{
    int idx = blockIdx.x * 256 + threadIdx.x;   // 2048*1024
    int i = idx >> 10, n = idx & 1023;
    float4 r = *(const float4*)&rot[i * 4];
    float4 w = *(const float4*)&Wrot[n * 4];
    float v = r.x * w.x + r.y * w.y + r.z * w.z + r.w * w.w;
    int h = 16 + (n >> 7), cc = n & 127;
    ushort u = f2h(v);
    if (cc < 64) Kbuf[(h * S_LEN + i) * CDIM + cc] = u;
    else         Qbuf[(h * S_LEN + i) * CDIM + cc - 64] = u;
}

__global__ __launch_bounds__(256) void zero_kernel(float* __restrict__ p) {
    p[blockIdx.x * 256 + threadIdx.x] = 0.f;
}

// Flash attention per (head, 64-row i-tile). Block = 4 waves, wave owns 16 i-rows.
// LDS: Q/V rows padded 64->72 ushorts (2-way banks = free); P kept at stride 64
// with XOR swizzle col ^= (row&7)*8 (keeps 54272 B total -> 3 blocks/CU).
__global__ __launch_bounds__(256) void flash_kernel(
    const ushort* __restrict__ Kbuf, const ushort* __restrict__ Qbuf,
    const ushort* __restrict__ Vt, float* __restrict__ Oacc)
{
    __shared__ ushort Qlds[64 * 72];     // [j'][c], stride 72
    __shared__ ushort Vlds[256 * 72];    // [d][j'], stride 72
    __shared__ ushort Plds[4][16 * 64];  // per wave: [i'][j'^swz], stride 64

    const int tid = threadIdx.x;
    const int wave = tid >> 6, lane = tid & 63;
    const int g = lane >> 4, c = lane & 15;
    const int h = blockIdx.y;
    const int i0 = blockIdx.x * 64 + wave * 16;
    const float SC = 0.51006973f;        // log2(e)/sqrt(8)

    const ushort* Krow = &Kbuf[(h * S_LEN + i0 + c) * CDIM + g * 8];
    f16x8 ka0 = *(const f16x8*)Krow;
    f16x8 ka1 = *(const f16x8*)(Krow + 32);

    f32x4 acc[16];
#pragma unroll
    for (int t = 0; t < 16; t++) acc[t] = f32x4{0, 0, 0, 0};
    float mrow[4] = {-1e30f, -1e30f, -1e30f, -1e30f};
    float lrow[4] = {0.f, 0.f, 0.f, 0.f};

    for (int j0 = 0; j0 < S_LEN; j0 += 64) {
        __syncthreads();   // previous iter's LDS reads complete before restage
        {
            // Q tile: 64 rows x 64 ushorts, 8 int4-chunks per row
            const int4* Qg = (const int4*)&Qbuf[(h * S_LEN + j0) * CDIM];
#pragma unroll
            for (int q = 0; q < 2; q++) {
                int idx = tid + 256 * q;             // 0..511
                int row = idx >> 3, ch = idx & 7;
                *(int4*)&Qlds[row * 72 + ch * 8] = Qg[idx];
            }
            // V tile: 256 rows (d) x 64 cols (j'), 8 int4-chunks per row
#pragma unroll
            for (int q = 0; q < 8; q++) {
                int i4 = tid + 256 * q;              // 0..2047
                int d = i4 >> 3, jq = i4 & 7;
                *(int4*)&Vlds[d * 72 + jq * 8] =
                    *(const int4*)&Vt[(h * DDIM + d) * S_LEN + j0 + jq * 8];
            }
        }
        __syncthreads();

        // scores: S[i'][j'] for 16 rows x 64 cols, 4 j-chunks
        f32x4 Sf[4];
#pragma unroll
        for (int jc = 0; jc < 4; jc++) {
            const ushort* Qr = &Qlds[(jc * 16 + c) * 72 + g * 8];
            f16x8 qb0 = *(const f16x8*)Qr;
            f16x8 qb1 = *(const f16x8*)(Qr + 32);
            f32x4 s = {0, 0, 0, 0};
            s = __builtin_amdgcn_mfma_f32_16x16x32_f16(ka0, qb0, s, 0, 0, 0);
            s = __builtin_amdgcn_mfma_f32_16x16x32_f16(ka1, qb1, s, 0, 0, 0);
#pragma unroll
            for (int r = 0; r < 4; r++) Sf[jc][r] = s[r] * SC;   // exp2 domain
        }

        // online softmax: row stats live in lanes sharing g (16-lane groups)
        float nm[4], alpha[4], rs[4];
#pragma unroll
        for (int r = 0; r < 4; r++)
            nm[r] = fmaxf(fmaxf(Sf[0][r], Sf[1][r]), fmaxf(Sf[2][r], Sf[3][r]));
#pragma unroll
        for (int off = 1; off < 16; off <<= 1)
#pragma unroll
            for (int r = 0; r < 4; r++) nm[r] = fmaxf(nm[r], __shfl_xor(nm[r], off));
#pragma unroll
        for (int r = 0; r < 4; r++) {
            nm[r] = fmaxf(nm[r], mrow[r]);
            alpha[r] = exp2f(mrow[r] - nm[r]);
            rs[r] = 0.f;
        }
#pragma unroll
        for (int jc = 0; jc < 4; jc++)
#pragma unroll
            for (int r = 0; r < 4; r++) {
                float p = exp2f(Sf[jc][r] - nm[r]);
                rs[r] += p;
                int row = g * 4 + r;
                int col = (jc * 16 + c) ^ ((row & 7) << 3);   // XOR swizzle
                Plds[wave][row * 64 + col] = f2h(p);
            }
#pragma unroll
        for (int off = 1; off < 16; off <<= 1)
#pragma unroll
            for (int r = 0; r < 4; r++) rs[r] += __shfl_xor(rs[r], off);
#pragma unroll
        for (int r = 0; r < 4; r++) {
            lrow[r] = lrow[r] * alpha[r] + rs[r];
            mrow[r] = nm[r];
        }
#pragma unroll
        for (int t = 0; t < 16; t++)
#pragma unroll
            for (int r = 0; r < 4; r++) acc[t][r] *= alpha[r];

        __syncthreads();   // Plds visible (and keeps waves in step)

        // PV: P (16x64) @ V (64x256); P a-frag row c, cols g*8.. via swizzle
        f16x8 pa0 = *(const f16x8*)&Plds[wave][c * 64 + ((g * 8) ^ ((c & 7) << 3))];
        f16x8 pa1 = *(const f16x8*)&Plds[wave][c * 64 + ((g * 8 + 32) ^ ((c & 7) << 3))];
#pragma unroll
        for (int t = 0; t < 16; t++) {
            f16x8 vb0 = *(const f16x8*)&Vlds[(t * 16 + c) * 72 + g * 8];
            f16x8 vb1 = *(const f16x8*)&Vlds[(t * 16 + c) * 72 + 32 + g * 8];
            acc[t] = __builtin_amdgcn_mfma_f32_16x16x32_f16(pa0, vb0, acc[t], 0, 0, 0);
            acc[t] = __builtin_amdgcn_mfma_f32_16x16x32_f16(pa1, vb1, acc[t], 0, 0, 0);
        }
    }

    // accumulate head partial into shared f32 output (24 heads -> same address)
#pragma unroll
    for (int t = 0; t < 16; t++)
#pragma unroll
        for (int r = 0; r < 4; r++) {
            int i = i0 + g * 4 + r;
            int d = t * 16 + c;
            atomicAdd(&Oacc[i * DDIM + d], acc[t][r] / lrow[r]);
        }
}

__global__ __launch_bounds__(256) void convert_kernel(
    const float* __restrict__ Oacc, float* __restrict__ out)
{
    int idx = blockIdx.x * 256 + threadIdx.x;   // 2048*256
    out[idx] = Oacc[idx];
}

extern "C" void kernel_launch(void* const* d_in, const int* in_sizes, int n_in,
                              void* d_out, int out_size, void* d_ws, size_t ws_size,
                              hipStream_t stream) {
    // Inputs: f32, resolved by element count (safety net), dict-order fallback.
    const float *nodes = 0, *aux = 0, *rot = 0, *W_nodes = 0, *b_nodes = 0,
                *W_aux = 0, *b_aux = 0, *W_rot = 0, *W_val = 0, *b_val = 0;
    int i1024[2] = {-1, -1};
    int n1024 = 0;
    for (int i = 0; i < n_in; ++i) {
        const float* p = (const float*)d_in[i];
        switch (in_sizes[i]) {
            case 524288:  nodes   = p; break;
            case 131072:  aux     = p; break;
            case 8192:    rot     = p; break;
            case 262144:  W_nodes = p; break;
            case 65536:   W_aux   = p; break;
            case 4096:    W_rot   = p; break;
            case 1572864: W_val   = p; break;
            case 6144:    b_val   = p; break;
            case 1024:    if (n1024 < 2) i1024[n1024] = i; n1024++; break;
            default: break;
        }
    }
    if (n1024 == 2) {
        b_nodes = (const float*)d_in[i1024[0]];
        b_aux   = (const float*)d_in[i1024[1]];
    }
    if (!nodes || !aux || !rot || !W_nodes || !b_nodes || !W_aux || !b_aux ||
        !W_rot || !W_val || !b_val) {
        nodes   = (const float*)d_in[0];
        aux     = (const float*)d_in[1];
        rot     = (const float*)d_in[2];
        W_nodes = (const float*)d_in[3];
        b_nodes = (const float*)d_in[4];
        W_aux   = (const float*)d_in[5];
        b_aux   = (const float*)d_in[6];
        W_rot   = (const float*)d_in[7];
        W_val   = (const float*)d_in[8];
        b_val   = (const float*)d_in[9];
    }
    float* out = (float*)d_out;   // reference output dtype is float32

    // ws layout: Oacc f32 (2MB) | K f16 (6.29MB) | Q f16 (6.29MB) | Vt f16 (25.2MB)
    float*  Oacc = (float*)d_ws;
    ushort* Kbuf = (ushort*)(Oacc + S_LEN * DDIM);
    ushort* Qbuf = Kbuf + NHEAD * S_LEN * CDIM;
    ushort* Vt   = Qbuf + NHEAD * S_LEN * CDIM;

    dim3 blk(256);
    zero_kernel<<<dim3(S_LEN * DDIM / 256), blk, 0, stream>>>(Oacc);
    // nodes -> k/q heads 0..7:  M=2048 N=1024 K=256
    gemm_bt_kernel<<<dim3(16, 32), blk, 0, stream>>>(nodes, W_nodes, b_nodes,
        2048, 1024, 256, 0, 0, Kbuf, Qbuf, nullptr);
    // aux -> k/q heads 8..15:  M=2048 N=1024 K=64
    gemm_bt_kernel<<<dim3(16, 32), blk, 0, stream>>>(aux, W_aux, b_aux,
        2048, 1024, 64, 0, 8, Kbuf, Qbuf, nullptr);
    // rot -> k/q heads 16..23 (K=4, no bias)
    rot_proj_kernel<<<dim3(8192), blk, 0, stream>>>(rot, W_rot, Kbuf, Qbuf);
    // nodes -> values, transposed write: M=2048 N=6144 K=256
    gemm_bt_kernel<<<dim3(96, 32), blk, 0, stream>>>(nodes, W_val, b_val,
        2048, 6144, 256, 1, 0, nullptr, nullptr, Vt);
    // attention: 24 heads x 32 i-tiles, accumulate into Oacc
    flash_kernel<<<dim3(32, NHEAD), blk, 0, stream>>>(Kbuf, Qbuf, Vt, Oacc);
    // f32 copy to out
    convert_kernel<<<dim3(2048), blk, 0, stream>>>(Oacc, out);
}